// Round 8
// baseline (28.445 us; speedup 1.0000x reference)
//
#include <hip/hip_runtime.h>
#include <hip/hip_bf16.h>

#define BS 32
#define NQ 300
#define NC 92
#define NT 50
#define Q_TOT (BS * NQ)   // 9600
#define T_TOT (BS * NT)   // 1600
#define QPB 8             // q-rows per block (9600 = 1200 * 8)
#define TPB 320           // threads per block = targets per block (1600 = 5*320)

// d_ws layout (floats):
//   probs [Q_TOT * NC]                      (3.53 MB)
//   qcx/qcy/qhw/qhh/qar [5 * Q_TOT]         (192 KB)
#define WS_PROBS 0
#define WS_QCX   (Q_TOT * NC)
#define WS_QCY   (WS_QCX + Q_TOT)
#define WS_QHW   (WS_QCX + 2 * Q_TOT)
#define WS_QHH   (WS_QCX + 3 * Q_TOT)
#define WS_QAR   (WS_QCX + 4 * Q_TOT)

// K1: one wave per query row. Full softmax prob row -> ws, plus SoA box params
// (cx, cy, w/2, h/2, area) so K2's q-side is 5 uniform scalar loads.
__global__ __launch_bounds__(256) void prep_kernel(
    const float* __restrict__ logits,   // [Q_TOT, NC]
    const float* __restrict__ boxes,    // [Q_TOT, 4] cxcywh
    float* __restrict__ ws)
{
    const int row  = blockIdx.x * 4 + (threadIdx.x >> 6);
    const int lane = threadIdx.x & 63;

    const float* rp = logits + (size_t)row * NC;
    float x0 = (lane < NC)      ? rp[lane]      : -INFINITY;
    float x1 = (lane + 64 < NC) ? rp[lane + 64] : -INFINITY;

    float m = fmaxf(x0, x1);
    #pragma unroll
    for (int off = 1; off < 64; off <<= 1)
        m = fmaxf(m, __shfl_xor(m, off));

    const float e0 = __expf(x0 - m);    // exp(-inf - m) == 0 for pad lanes
    const float e1 = __expf(x1 - m);
    float s = e0 + e1;
    #pragma unroll
    for (int off = 1; off < 64; off <<= 1)
        s += __shfl_xor(s, off);

    const float inv = 1.0f / s;
    float* pr = ws + WS_PROBS + (size_t)row * NC;
    if (lane < NC)      pr[lane]      = e0 * inv;
    if (lane + 64 < NC) pr[lane + 64] = e1 * inv;

    if (lane == 0) {
        const float4 b = *reinterpret_cast<const float4*>(boxes + 4 * row);
        ws[WS_QCX + row] = b.x;
        ws[WS_QCY + row] = b.y;
        ws[WS_QHW + row] = 0.5f * b.z;
        ws[WS_QHH + row] = 0.5f * b.w;
        ws[WS_QAR + row] = b.z * b.w;
    }
}

// K2: thread = one target t; 8 q-rows. Probs staged into LDS (coalesced),
// per-element class lookup = 1 ds_read. Minimal scalar f32 math:
//   mx  = max(|u|,|v|)  (abs input modifiers, free)
//   dx  = h - mx;  iw = max(dx,0);  ew = 2h - dx  (fma, no min/max)
//   giou = (inter*earea - ue + uni^2) * rcp(ue)   (single trans)
//   res = fma(-num, rc, (l1 - p))
__global__ __launch_bounds__(TPB) void cost_kernel(
    const int*   __restrict__ tgt_labels,   // [T_TOT]
    const float* __restrict__ tgt_boxes,    // [T_TOT, 4] cxcywh
    const float* __restrict__ ws,           // probs + SoA q tables
    float* __restrict__ out)                // [Q_TOT, T_TOT]
{
    __shared__ float sp[QPB * NC];          // 736 floats = 2.9 KB

    const int tid = threadIdx.x;
    const int t   = blockIdx.x * TPB + tid;
    const int q0  = blockIdx.y * QPB;

    // Stage this block's 8 prob rows, coalesced.
    {
        const float* gp = ws + WS_PROBS + (size_t)q0 * NC;
        for (int i = tid; i < QPB * NC; i += TPB)
            sp[i] = gp[i];
    }

    // t-side in registers.
    const float4 tb = *reinterpret_cast<const float4*>(tgt_boxes + 4 * t);
    const float tcx = tb.x, tcy = tb.y;
    const float thw = 0.5f * tb.z, thh = 0.5f * tb.w;
    const float tar = tb.z * tb.w;
    const int lbl = tgt_labels[t];

    __syncthreads();

    const float* qcx_t = ws + WS_QCX;
    const float* qcy_t = ws + WS_QCY;
    const float* qhw_t = ws + WS_QHW;
    const float* qhh_t = ws + WS_QHH;
    const float* qar_t = ws + WS_QAR;
    float* op = out + (size_t)q0 * T_TOT + t;

    #pragma unroll
    for (int i = 0; i < QPB; ++i) {
        const int q = q0 + i;                    // block-uniform -> s_loads
        const float qcx = qcx_t[q], qcy = qcy_t[q];
        const float qhw = qhw_t[q], qhh = qhh_t[q];
        const float qar = qar_t[q];

        const float p = sp[i * NC + lbl];        // ds_read_b32, imm offset

        const float ux = qcx - tcx, uy = qcy - tcy;
        const float vx = qhw - thw, vy = qhh - thh;
        const float hx = qhw + thw, hy = qhh + thh;

        const float mx = fmaxf(fabsf(ux), fabsf(vx));   // abs = input mods
        const float my = fmaxf(fabsf(uy), fabsf(vy));
        const float dx = hx - mx, dy = hy - my;
        const float iw = fmaxf(dx, 0.0f), ih = fmaxf(dy, 0.0f);
        const float inter = iw * ih;
        const float ew = fmaf(2.0f, hx, -dx);    // enclosing = 2h - d
        const float eh = fmaf(2.0f, hy, -dy);
        const float earea = ew * eh;

        const float uni = (qar + tar) - inter;
        const float ue  = uni * earea;
        const float rc  = __builtin_amdgcn_rcpf(ue);
        float num = inter * earea - ue;
        num = fmaf(uni, uni, num);               // num = giou * ue

        // l1 = |ux|+2|vx| + |uy|+2|vy|  (abs input mods on fma)
        const float l1 = fmaf(2.0f, fabsf(vx), fabsf(ux))
                       + fmaf(2.0f, fabsf(vy), fabsf(uy));

        // res = l1 - p - giou = fma(-num, rc, l1 - p)
        op[i * T_TOT] = fmaf(-num, rc, l1 - p);
    }
}

extern "C" void kernel_launch(void* const* d_in, const int* in_sizes, int n_in,
                              void* d_out, int out_size, void* d_ws, size_t ws_size,
                              hipStream_t stream) {
    const float* pred_logits = (const float*)d_in[0]; // [32,300,92]
    const float* pred_boxes  = (const float*)d_in[1]; // [32,300,4]
    const int*   tgt_labels  = (const int*)d_in[2];   // [32,50]
    const float* tgt_boxes   = (const float*)d_in[3]; // [32,50,4]
    float* out = (float*)d_out;                       // [32,300,1600]
    float* ws  = (float*)d_ws;                        // 3.72 MB used

    prep_kernel<<<Q_TOT / 4, 256, 0, stream>>>(pred_logits, pred_boxes, ws);

    dim3 grid(T_TOT / TPB, Q_TOT / QPB);              // (5, 1200)
    cost_kernel<<<grid, TPB, 0, stream>>>(tgt_labels, tgt_boxes, ws, out);
}